// Round 2
// baseline (685.096 us; speedup 1.0000x reference)
//
#include <hip/hip_runtime.h>
#include <math.h>

// Problem constants (B=2, H=W=256, DIM=INNER=64, WS=8, OWS=12, HEADS=4, DH=16)
#define NPIX   65536      // 256*256
#define NPIXT  131072     // B * NPIX
#define NW     1024       // 32*32 windows per batch
#define KEEP   512
#define PITCH  68         // LDS row pitch (floats): mult of 4 for float4 ops

// Layouts: x, condition_global, h1, sa, out = NCHW (as given / required).
// qs, ks, vs, amix = NHWC: t[(b*NPIX + p)*64 + c]  (64 contiguous ch/pixel).

// ---------------------------------------------------------------------------
// K1: fused q/k/v 1x1 convs.  OG-SPLIT version: block = 256 thr = 64 px x
// 4 og-groups (wave w handles og=w for all 64 px).  Per (px,og) the inner
// computation (acc[3][16], c ascending 0..63, m-inner) is INSTRUCTION-
// IDENTICAL to the round-0 kernel -> bit-identical outputs.
// Why: round-0 ran 512 blocks x 4 waves = 8 waves/CU (64 KB LDS also capped
// 2 blocks/CU); VALU issue is only ~5 us/SIMD so the 127 us was unhidden
// latency.  og-split gives 4x threads (2048 blocks x 4 waves = 32 waves/CU)
// with acc[3][16]=48 regs -> <=64 VGPR, no spill (round-1 lesson: the
// allocator will NOT exceed 64 willingly; acc[64] spilled to scratch).
// Bonus: the 4 og-quarters of each 256 B output span are written by 4
// concurrent waves -> L2 merges full lines (round-0 write amp was 1.8x).
// ---------------------------------------------------------------------------
__global__ __launch_bounds__(256) void k_qkv(
    const float* __restrict__ x,
    const float* __restrict__ Wq, const float* __restrict__ bq,
    const float* __restrict__ Wk, const float* __restrict__ bk,
    const float* __restrict__ Wv, const float* __restrict__ bv,
    float* __restrict__ qs, float* __restrict__ ks, float* __restrict__ vs)
{
    __shared__ float xs[64][64];                 // 16 KB
    const int tid  = threadIdx.x;
    const int px   = tid & 63;                   // pixel within tile
    const int og   = tid >> 6;                   // wave index = output group
    const int tile = blockIdx.x;                 // 0..2047
    const int b    = tile >> 10;
    const int p0   = (tile & 1023) << 6;         // tile's first pixel
    const int gp   = (b << 16) + p0 + px;        // global pixel

    // stage 64 px x 64 ch (1024 float4, 4 per thread), coalesced 256 B rows
    #pragma unroll
    for (int it = 0; it < 4; ++it) {
        const int i = it * 256 + tid;
        const int c = i >> 4;
        const int f = i & 15;
        *(float4*)&xs[c][f * 4] =
            *(const float4*)(x + ((size_t)(b * 64 + c)) * NPIX + p0 + f * 4);
    }
    __syncthreads();

    const float* Ws[3]   = {Wq, Wk, Wv};
    const float* bias[3] = {bq, bk, bv};
    float* outs[3] = {qs + (size_t)gp * 64, ks + (size_t)gp * 64, vs + (size_t)gp * 64};

    float acc[3][16];
    #pragma unroll
    for (int m = 0; m < 3; ++m)
        #pragma unroll
        for (int j = 0; j < 16; ++j) acc[m][j] = 0.f;

    #pragma unroll 2
    for (int c = 0; c < 64; ++c) {
        const float xv = xs[c][px];
        #pragma unroll
        for (int m = 0; m < 3; ++m) {
            const float* W = Ws[m];
            #pragma unroll
            for (int j = 0; j < 16; ++j)
                acc[m][j] += W[(og * 16 + j) * 64 + c] * xv;
        }
    }
    #pragma unroll
    for (int m = 0; m < 3; ++m) {
        const float* bb = bias[m];
        #pragma unroll
        for (int j4 = 0; j4 < 4; ++j4) {
            float4 v;
            v.x = acc[m][j4 * 4 + 0] + bb[og * 16 + j4 * 4 + 0];
            v.y = acc[m][j4 * 4 + 1] + bb[og * 16 + j4 * 4 + 1];
            v.z = acc[m][j4 * 4 + 2] + bb[og * 16 + j4 * 4 + 2];
            v.w = acc[m][j4 * 4 + 3] + bb[og * 16 + j4 * 4 + 3];
            *(float4*)(outs[m] + og * 16 + j4 * 4) = v;
        }
    }
}

// ---------------------------------------------------------------------------
// K2: conditioning conv (68 -> 17) + channel LayerNorm + lrelu; emits xm.
// (unchanged)
// ---------------------------------------------------------------------------
__global__ __launch_bounds__(256) void k_cond(
    const float* __restrict__ vs, const float* __restrict__ cg,
    const float* __restrict__ pinW, const float* __restrict__ pinb,
    const float* __restrict__ lnw, const float* __restrict__ lnb,
    float* __restrict__ h1, float* __restrict__ xm)
{
    const int gp = blockIdx.x * 256 + threadIdx.x;
    const int b  = gp >> 16;
    const int p  = gp & 65535;
    const int h  = p >> 8;
    const int w  = p & 255;

    float acc[17];
    #pragma unroll
    for (int oc = 0; oc < 17; ++oc) acc[oc] = pinb[oc];

    const float* vp = vs + (size_t)gp * 64;
    #pragma unroll 4
    for (int c4 = 0; c4 < 16; ++c4) {
        const float4 v4 = *(const float4*)(vp + c4 * 4);
        const float vv[4] = {v4.x, v4.y, v4.z, v4.w};
        #pragma unroll
        for (int k = 0; k < 4; ++k) {
            const int c = c4 * 4 + k;
            #pragma unroll
            for (int oc = 0; oc < 17; ++oc)
                acc[oc] += pinW[oc * 68 + c] * vv[k];
        }
    }
    const float c64 = cg[(b * 2 + 0) * NPIX + p];
    const float c65 = cg[(b * 2 + 1) * NPIX + p];
    const float c66 = -1.f + 2.f * (float)(h & 7) / 7.f;
    const float c67 = -1.f + 2.f * (float)(w & 7) / 7.f;
    #pragma unroll
    for (int oc = 0; oc < 17; ++oc)
        acc[oc] += pinW[oc * 68 + 64] * c64 + pinW[oc * 68 + 65] * c65 +
                   pinW[oc * 68 + 66] * c66 + pinW[oc * 68 + 67] * c67;

    float u = 0.f;
    #pragma unroll
    for (int oc = 0; oc < 17; ++oc) u += acc[oc];
    u *= (1.f / 17.f);
    float s = 0.f;
    #pragma unroll
    for (int oc = 0; oc < 17; ++oc) { const float d = acc[oc] - u; s += d * d; }
    s *= (1.f / 17.f);
    const float rstd = rsqrtf(s + 1e-6f);

    float xsum = 0.f;
    #pragma unroll
    for (int oc = 0; oc < 17; ++oc) {
        float hv = lnw[oc] * (acc[oc] - u) * rstd + lnb[oc];
        hv = (hv >= 0.f) ? hv : 0.1f * hv;
        h1[(b * 17 + oc) * NPIX + p] = hv;
        xsum += hv;
    }
    xm[gp] = xsum * (1.f / 17.f);
}

// ---------------------------------------------------------------------------
// K3: 3x3 conv (17 -> 1) + sigmoid -> sa.  (unchanged)
// ---------------------------------------------------------------------------
__global__ __launch_bounds__(256) void k_sa(
    const float* __restrict__ h1, const float* __restrict__ saW,
    const float* __restrict__ sab, float* __restrict__ sa)
{
    __shared__ float S[17 * 3 * 256];
    const int tid = threadIdx.x;
    const int b   = blockIdx.x >> 8;
    const int row = blockIdx.x & 255;

    for (int i = tid; i < 3264; i += 256) {
        const int ch  = i / 192;
        const int rem = i - ch * 192;
        const int dr  = rem >> 6;
        const int c4  = rem & 63;
        const int rr  = row + dr - 1;
        float4 v = {0.f, 0.f, 0.f, 0.f};
        if ((unsigned)rr < 256u)
            v = *(const float4*)(h1 + ((size_t)(b * 17 + ch)) * NPIX + rr * 256 + c4 * 4);
        *(float4*)&S[(ch * 3 + dr) * 256 + c4 * 4] = v;
    }
    __syncthreads();

    const int w = tid;
    float acc = sab[0];
    #pragma unroll 1
    for (int ch = 0; ch < 17; ++ch) {
        #pragma unroll
        for (int dr = 0; dr < 3; ++dr) {
            const float* Sp = &S[(ch * 3 + dr) * 256];
            const float m  = Sp[w];
            const float l  = (w > 0)   ? Sp[w - 1] : 0.f;
            const float r_ = (w < 255) ? Sp[w + 1] : 0.f;
            const float* Wp = saW + (ch * 3 + dr) * 3;
            acc += Wp[0] * l + Wp[1] * m + Wp[2] * r_;
        }
    }
    sa[b * NPIX + row * 256 + w] = 1.f / (1.f + __expf(-acc));
}

// ---------------------------------------------------------------------------
// K4: window scoring MLP + stable-argsort partition.  (unchanged)
// ---------------------------------------------------------------------------
__global__ __launch_bounds__(1024) void k_score_select(
    const float* __restrict__ xm,
    const float* __restrict__ m1W, const float* __restrict__ m1b,
    const float* __restrict__ m2W, const float* __restrict__ m2b,
    int* __restrict__ flag, int* __restrict__ kept)
{
    __shared__ float sc[NW];
    const int b = blockIdx.x;
    const int t = threadIdx.x;
    const int i = t >> 5;
    const int j = t & 31;

    float z[8];
    #pragma unroll
    for (int jj = 0; jj < 8; ++jj) z[jj] = m1b[jj];

    for (int a = 0; a < 8; ++a) {
        #pragma unroll
        for (int cc = 0; cc < 8; ++cc) {
            const float xv = xm[b * NPIX + (i * 8 + a) * 256 + (j * 8 + cc)];
            const int tt = a * 8 + cc;
            #pragma unroll
            for (int jj = 0; jj < 8; ++jj)
                z[jj] += m1W[jj * 64 + tt] * xv;
        }
    }
    #pragma unroll
    for (int jj = 0; jj < 8; ++jj) z[jj] = (z[jj] >= 0.f) ? z[jj] : 0.1f * z[jj];

    float l0 = m2b[0], l1 = m2b[1];
    #pragma unroll
    for (int jj = 0; jj < 8; ++jj) { l0 += m2W[jj] * z[jj]; l1 += m2W[8 + jj] * z[jj]; }
    const float mx = fmaxf(l0, l1);
    const float e0 = expf(l0 - mx), e1 = expf(l1 - mx);
    sc[t] = e0 / (e0 + e1);
    __syncthreads();

    const float s = sc[t];
    int cnt = 0;
    for (int jq = 0; jq < NW; ++jq) {
        const float sj = sc[jq];
        cnt += (sj > s) || (sj == s && jq < t);
    }
    flag[b * NW + t] = (cnt < KEEP) ? 1 : 0;
    if (cnt < KEEP) kept[b * KEEP + cnt] = t;
}

// ---------------------------------------------------------------------------
// K5: windowed attention.  Same staging/FP order as round 0; the inner core
// is restructured to fit in 64 VGPRs with ZERO spill (round-0 evidence:
// VGPR=64 vs ~93 live floats -> ~20-30 spilled, WRITE_SIZE 36.9 MB vs 16.8
// ideal = spill traffic; VALUBusy 4.4%).  Changes:
//   (1) kreg[18]/vreg[18] arrays eliminated: per 4-key group, 2 just-in-time
//       lane-strided ds_read_b32 with a one-group register prefetch.
//   (2) chh[12] -> per-chunk chc[6] (6 fewer live regs; each value computed
//       with the identical instruction sequence, just later).
//   (3) readlanes batched; results are wave-uniform -> live in SGPRs.
// Per-key arithmetic and key order (kl = 0..143 ascending, s = chh+cw then
// ascending-d dot, sum += e, ascending-d PV) is instruction-identical.
// ---------------------------------------------------------------------------
__global__ __launch_bounds__(256) void k_attn(
    const float* __restrict__ qs, const float* __restrict__ ks,
    const float* __restrict__ vs, const int* __restrict__ kept,
    const float* __restrict__ relh, const float* __restrict__ relw,
    float* __restrict__ amix)
{
    __shared__ float SK[72 * PITCH];   // 19584 B
    __shared__ float SV[72 * PITCH];   // 19584 B

    const int b    = blockIdx.y;
    const int win  = kept[b * KEEP + blockIdx.x];
    const int wy = win >> 5, wx = win & 31;
    const int tid  = threadIdx.x;
    const int head = tid >> 6;
    const int lane = tid & 63;
    const int choff = head * 16;
    const size_t bbase = (size_t)b * NPIX;
    const int px0 = (wy * 8) * 256 + wx * 8;      // window origin pixel

    // ---- phase 0: cooperative q stage (64 px x 64 ch = 1024 float4) ----
    #pragma unroll
    for (int it = 0; it < 4; ++it) {
        const int i  = it * 256 + tid;
        const int px = i >> 4;
        const int c4 = i & 15;
        const float4 v = *(const float4*)(
            qs + (bbase + px0 + (px >> 3) * 256 + (px & 7)) * 64 + c4 * 4);
        *(float4*)&SK[px * PITCH + c4 * 4] = v;
    }
    __syncthreads();

    const int qrow = lane >> 3, qcol = lane & 7;
    float q[16];
    #pragma unroll
    for (int j4 = 0; j4 < 4; ++j4) {
        const float4 v = *(const float4*)&SK[(qrow * 8 + qcol) * PITCH + choff + j4 * 4];
        q[j4 * 4 + 0] = v.x * 0.25f; q[j4 * 4 + 1] = v.y * 0.25f;
        q[j4 * 4 + 2] = v.z * 0.25f; q[j4 * 4 + 3] = v.w * 0.25f;
    }

    // ---- column rel-pos coefficients (identical arithmetic to round 0) ----
    float cw[12];
    #pragma unroll
    for (int k = 0; k < 12; ++k) {
        const float* rw = relw + (k - qcol + 11) * 16;
        float sw = 0.f;
        #pragma unroll
        for (int j4 = 0; j4 < 4; ++j4) {
            const float4 w4 = *(const float4*)(rw + j4 * 4);
            sw += q[j4*4+0]*w4.x + q[j4*4+1]*w4.y + q[j4*4+2]*w4.z + q[j4*4+3]*w4.w;
        }
        cw[k] = sw;
    }

    const int sub = lane >> 4;       // kp % 4
    const int d_  = lane & 15;       // channel within head
    const int wy8 = wy * 8 - 2, wx8 = wx * 8 - 2;

    float sum = 0.f;
    float vo[16];
    #pragma unroll
    for (int d = 0; d < 16; ++d) vo[d] = 0.f;

    #pragma unroll 1
    for (int c = 0; c < 2; ++c) {
        __syncthreads();    // prior LDS reads complete before restaging
        // ---- stage 6 patch rows of K and V (each 72 px x 64 ch) ----
        for (int i = tid; i < 1152; i += 256) {
            const int pxl = i >> 4;             // 0..71
            const int c4  = i & 15;
            const int rl  = pxl / 12;
            const int col = pxl - rl * 12;
            const int ry  = wy8 + 6 * c + rl;
            const int cx  = wx8 + col;
            float4 kv = {0.f,0.f,0.f,0.f}, vv = {0.f,0.f,0.f,0.f};
            if ((unsigned)ry < 256u && (unsigned)cx < 256u) {
                const size_t g = (bbase + ry * 256 + cx) * 64 + c4 * 4;
                kv = *(const float4*)(ks + g);
                vv = *(const float4*)(vs + g);
            }
            *(float4*)&SK[pxl * PITCH + c4 * 4] = kv;
            *(float4*)&SV[pxl * PITCH + c4 * 4] = vv;
        }
        __syncthreads();

        // ---- row rel-pos coefficients for this chunk's 6 rows ----
        // (same instruction sequence as round-0's chh[c*6+rl])
        float chc[6];
        #pragma unroll
        for (int rl = 0; rl < 6; ++rl) {
            const float* rh = relh + (c * 6 + rl - qrow + 11) * 16;
            float sh = 0.f;
            #pragma unroll
            for (int j4 = 0; j4 < 4; ++j4) {
                const float4 h4 = *(const float4*)(rh + j4 * 4);
                sh += q[j4*4+0]*h4.x + q[j4*4+1]*h4.y + q[j4*4+2]*h4.z + q[j4*4+3]*h4.w;
            }
            chc[rl] = sh;
        }

        // ---- QK + exp + PV over 72 keys, JIT K/V with 1-group prefetch ----
        // lane (sub,d_) holds element (pixel 4g+sub, ch choff+d_) of group g.
        float kg = SK[sub * PITCH + choff + d_];
        float vg = SV[sub * PITCH + choff + d_];
        #pragma unroll
        for (int g = 0; g < 18; ++g) {
            float kn = 0.f, vn = 0.f;
            if (g < 17) {
                const int a = (4 * (g + 1) + sub) * PITCH + choff + d_;
                kn = SK[a];
                vn = SV[a];
            }
            #pragma unroll
            for (int kk = 0; kk < 4; ++kk) {
                const int kl  = g * 4 + kk;      // 0..71, ascending (= rl*12+col)
                const int rl  = kl / 12;
                const int col = kl - rl * 12;
                float kd[16];
                #pragma unroll
                for (int d = 0; d < 16; ++d)
                    kd[d] = __int_as_float(__builtin_amdgcn_readlane(
                                __float_as_int(kg), kk * 16 + d));
                float s = chc[rl] + cw[col];
                #pragma unroll
                for (int d = 0; d < 16; ++d)
                    s += kd[d] * q[d];           // same ascending-d order
                const float e = __expf(s);
                sum += e;
                float vd[16];
                #pragma unroll
                for (int d = 0; d < 16; ++d)
                    vd[d] = __int_as_float(__builtin_amdgcn_readlane(
                                __float_as_int(vg), kk * 16 + d));
                #pragma unroll
                for (int d = 0; d < 16; ++d)
                    vo[d] += e * vd[d];          // same ascending-d order
            }
            kg = kn; vg = vn;
        }
    }

    // ---- epilogue: normalize, transpose via LDS, contiguous stores ----
    const float inv = 1.f / sum;
    __syncthreads();
    #pragma unroll
    for (int j4 = 0; j4 < 4; ++j4) {
        float4 v;
        v.x = vo[j4*4+0] * inv; v.y = vo[j4*4+1] * inv;
        v.z = vo[j4*4+2] * inv; v.w = vo[j4*4+3] * inv;
        *(float4*)&SK[(qrow * 8 + qcol) * PITCH + choff + j4 * 4] = v;
    }
    __syncthreads();
    #pragma unroll
    for (int it = 0; it < 4; ++it) {
        const int i  = it * 256 + tid;
        const int px = i >> 4;
        const int c4 = i & 15;
        const float4 v = *(const float4*)&SK[px * PITCH + c4 * 4];
        *(float4*)(amix + (bbase + px0 + (px >> 3) * 256 + (px & 7)) * 64 + c4 * 4) = v;
    }
}

// ---------------------------------------------------------------------------
// K6: final 1x1 conv (64 -> 64) with fused easy path.  (unchanged)
// ---------------------------------------------------------------------------
__global__ __launch_bounds__(256) void k_out_f(
    const float* __restrict__ amix, const float* __restrict__ vs,
    const float* __restrict__ sa, const int* __restrict__ flag,
    const float* __restrict__ W, const float* __restrict__ bias,
    float* __restrict__ out)
{
    __shared__ float xs[64][256];
    const int tid = threadIdx.x;
    const int gp  = blockIdx.x * 256 + tid;
    const int b   = gp >> 16;
    const int p   = gp & 65535;
    const int h   = p >> 8;
    const int w   = p & 255;

    const int win = (h >> 3) * 32 + (w >> 3);
    const int fl  = flag[b * NW + win];
    const float mult = fl ? 1.f : sa[gp];
    const float* src = (fl ? amix : vs) + (size_t)gp * 64;

    #pragma unroll
    for (int c4 = 0; c4 < 16; ++c4) {
        const float4 v = *(const float4*)(src + c4 * 4);
        xs[c4 * 4 + 0][tid] = v.x * mult;
        xs[c4 * 4 + 1][tid] = v.y * mult;
        xs[c4 * 4 + 2][tid] = v.z * mult;
        xs[c4 * 4 + 3][tid] = v.w * mult;
    }
    __syncthreads();

    const int base = (b << 6) * NPIX + p;
    for (int og = 0; og < 4; ++og) {
        float acc[16];
        #pragma unroll
        for (int j = 0; j < 16; ++j) acc[j] = 0.f;
        #pragma unroll 4
        for (int c = 0; c < 64; ++c) {
            const float xv = xs[c][tid];
            #pragma unroll
            for (int j = 0; j < 16; ++j)
                acc[j] += W[(og * 16 + j) * 64 + c] * xv;
        }
        #pragma unroll
        for (int j = 0; j < 16; ++j)
            out[base + (og * 16 + j) * NPIX] = acc[j] + bias[og * 16 + j];
    }
}

// ---------------------------------------------------------------------------
extern "C" void kernel_launch(void* const* d_in, const int* in_sizes, int n_in,
                              void* d_out, int out_size, void* d_ws, size_t ws_size,
                              hipStream_t stream)
{
    const float* x    = (const float*)d_in[0];
    const float* cg   = (const float*)d_in[1];
    const float* Wq   = (const float*)d_in[2];
    const float* bq   = (const float*)d_in[3];
    const float* Wk   = (const float*)d_in[4];
    const float* bk   = (const float*)d_in[5];
    const float* Wv   = (const float*)d_in[6];
    const float* bv   = (const float*)d_in[7];
    const float* Wout = (const float*)d_in[8];
    const float* bout = (const float*)d_in[9];
    const float* relh = (const float*)d_in[10];
    const float* relw = (const float*)d_in[11];
    const float* pinW = (const float*)d_in[12];
    const float* pinb = (const float*)d_in[13];
    const float* lnw  = (const float*)d_in[14];
    const float* lnb  = (const float*)d_in[15];
    const float* saW  = (const float*)d_in[16];
    const float* sab  = (const float*)d_in[17];
    const float* m1W  = (const float*)d_in[18];
    const float* m1b  = (const float*)d_in[19];
    const float* m2W  = (const float*)d_in[20];
    const float* m2b  = (const float*)d_in[21];
    float* out = (float*)d_out;

    // workspace layout (floats); qs doubles as the assembled "amix" tensor
    float* ws    = (float*)d_ws;
    float* qs    = ws;                       // 64*NPIXT (NHWC, aliased amix)
    float* ks    = qs + 8388608;             // NHWC
    float* vs    = ks + 8388608;             // NHWC
    float* h1    = vs + 8388608;             // 17 * NPIXT (NCHW)
    float* xm    = h1 + 17 * NPIXT;          // NPIXT
    float* sa    = xm + NPIXT;               // NPIXT
    int*   flag  = (int*)(sa + NPIXT);       // 2048
    int*   kept  = flag + 2048;              // 1024

    k_qkv         <<<2048, 256, 0, stream>>>(x, Wq, bq, Wk, bk, Wv, bv, qs, ks, vs);
    k_cond        <<<NPIXT / 256, 256, 0, stream>>>(vs, cg, pinW, pinb, lnw, lnb, h1, xm);
    k_sa          <<<512, 256, 0, stream>>>(h1, saW, sab, sa);
    k_score_select<<<2, 1024, 0, stream>>>(xm, m1W, m1b, m2W, m2b, flag, kept);
    k_attn        <<<dim3(KEEP, 2), 256, 0, stream>>>(qs, ks, vs, kept, relh, relw, qs);
    k_out_f       <<<NPIXT / 256, 256, 0, stream>>>(qs, vs, sa, flag, Wout, bout, out);
}

// Round 3
// 377.355 us; speedup vs baseline: 1.8155x; 1.8155x over previous
//
#include <hip/hip_runtime.h>
#include <math.h>

// Problem constants (B=2, H=W=256, DIM=INNER=64, WS=8, OWS=12, HEADS=4, DH=16)
#define NPIX   65536      // 256*256
#define NPIXT  131072     // B * NPIX
#define NW     1024       // 32*32 windows per batch
#define KEEP   512
#define PITCH  68         // LDS row pitch (floats): mult of 4 for float4 ops

// Layouts: x, condition_global, h1, sa, out = NCHW (as given / required).
// qs, ks, vs, amix = NHWC: t[(b*NPIX + p)*64 + c]  (64 contiguous ch/pixel).

// ---------------------------------------------------------------------------
// K1: fused q/k/v 1x1 convs, og-split (block = 64 px x 4 og-waves).
// ROUND-2 LESSON: og = tid>>6 is not provably wave-uniform -> all weight
// reads compiled to vector global_load (SGPR count fell 112->32), stalling
// every wave (VALUBusy 14%, 391 us).  readfirstlane(og) asserts uniformity
// -> weight offsets scalar -> s_load into SGPRs (round-0 codegen) while
// keeping 32 waves/CU.  Arithmetic unchanged (bit-identical).
// ---------------------------------------------------------------------------
__global__ __launch_bounds__(256) void k_qkv(
    const float* __restrict__ x,
    const float* __restrict__ Wq, const float* __restrict__ bq,
    const float* __restrict__ Wk, const float* __restrict__ bk,
    const float* __restrict__ Wv, const float* __restrict__ bv,
    float* __restrict__ qs, float* __restrict__ ks, float* __restrict__ vs)
{
    __shared__ float xs[64][64];                 // 16 KB
    const int tid  = threadIdx.x;
    const int px   = tid & 63;                   // pixel within tile
    const int og   = __builtin_amdgcn_readfirstlane(tid >> 6);  // wave-uniform
    const int tile = blockIdx.x;                 // 0..2047
    const int b    = tile >> 10;
    const int p0   = (tile & 1023) << 6;         // tile's first pixel
    const int gp   = (b << 16) + p0 + px;        // global pixel

    // stage 64 px x 64 ch (1024 float4, 4 per thread), coalesced 256 B rows
    #pragma unroll
    for (int it = 0; it < 4; ++it) {
        const int i = it * 256 + tid;
        const int c = i >> 4;
        const int f = i & 15;
        *(float4*)&xs[c][f * 4] =
            *(const float4*)(x + ((size_t)(b * 64 + c)) * NPIX + p0 + f * 4);
    }
    __syncthreads();

    const float* Ws[3]   = {Wq, Wk, Wv};
    const float* bias[3] = {bq, bk, bv};
    float* outs[3] = {qs + (size_t)gp * 64, ks + (size_t)gp * 64, vs + (size_t)gp * 64};

    float acc[3][16];
    #pragma unroll
    for (int m = 0; m < 3; ++m)
        #pragma unroll
        for (int j = 0; j < 16; ++j) acc[m][j] = 0.f;

    #pragma unroll 2
    for (int c = 0; c < 64; ++c) {
        const float xv = xs[c][px];
        #pragma unroll
        for (int m = 0; m < 3; ++m) {
            const float* W = Ws[m];
            #pragma unroll
            for (int j = 0; j < 16; ++j)
                acc[m][j] += W[(og * 16 + j) * 64 + c] * xv;
        }
    }
    #pragma unroll
    for (int m = 0; m < 3; ++m) {
        const float* bb = bias[m];
        #pragma unroll
        for (int j4 = 0; j4 < 4; ++j4) {
            float4 v;
            v.x = acc[m][j4 * 4 + 0] + bb[og * 16 + j4 * 4 + 0];
            v.y = acc[m][j4 * 4 + 1] + bb[og * 16 + j4 * 4 + 1];
            v.z = acc[m][j4 * 4 + 2] + bb[og * 16 + j4 * 4 + 2];
            v.w = acc[m][j4 * 4 + 3] + bb[og * 16 + j4 * 4 + 3];
            *(float4*)(outs[m] + og * 16 + j4 * 4) = v;
        }
    }
}

// ---------------------------------------------------------------------------
// K2: conditioning conv (68 -> 17) + channel LayerNorm + lrelu; emits xm.
// (unchanged)
// ---------------------------------------------------------------------------
__global__ __launch_bounds__(256) void k_cond(
    const float* __restrict__ vs, const float* __restrict__ cg,
    const float* __restrict__ pinW, const float* __restrict__ pinb,
    const float* __restrict__ lnw, const float* __restrict__ lnb,
    float* __restrict__ h1, float* __restrict__ xm)
{
    const int gp = blockIdx.x * 256 + threadIdx.x;
    const int b  = gp >> 16;
    const int p  = gp & 65535;
    const int h  = p >> 8;
    const int w  = p & 255;

    float acc[17];
    #pragma unroll
    for (int oc = 0; oc < 17; ++oc) acc[oc] = pinb[oc];

    const float* vp = vs + (size_t)gp * 64;
    #pragma unroll 4
    for (int c4 = 0; c4 < 16; ++c4) {
        const float4 v4 = *(const float4*)(vp + c4 * 4);
        const float vv[4] = {v4.x, v4.y, v4.z, v4.w};
        #pragma unroll
        for (int k = 0; k < 4; ++k) {
            const int c = c4 * 4 + k;
            #pragma unroll
            for (int oc = 0; oc < 17; ++oc)
                acc[oc] += pinW[oc * 68 + c] * vv[k];
        }
    }
    const float c64 = cg[(b * 2 + 0) * NPIX + p];
    const float c65 = cg[(b * 2 + 1) * NPIX + p];
    const float c66 = -1.f + 2.f * (float)(h & 7) / 7.f;
    const float c67 = -1.f + 2.f * (float)(w & 7) / 7.f;
    #pragma unroll
    for (int oc = 0; oc < 17; ++oc)
        acc[oc] += pinW[oc * 68 + 64] * c64 + pinW[oc * 68 + 65] * c65 +
                   pinW[oc * 68 + 66] * c66 + pinW[oc * 68 + 67] * c67;

    float u = 0.f;
    #pragma unroll
    for (int oc = 0; oc < 17; ++oc) u += acc[oc];
    u *= (1.f / 17.f);
    float s = 0.f;
    #pragma unroll
    for (int oc = 0; oc < 17; ++oc) { const float d = acc[oc] - u; s += d * d; }
    s *= (1.f / 17.f);
    const float rstd = rsqrtf(s + 1e-6f);

    float xsum = 0.f;
    #pragma unroll
    for (int oc = 0; oc < 17; ++oc) {
        float hv = lnw[oc] * (acc[oc] - u) * rstd + lnb[oc];
        hv = (hv >= 0.f) ? hv : 0.1f * hv;
        h1[(b * 17 + oc) * NPIX + p] = hv;
        xsum += hv;
    }
    xm[gp] = xsum * (1.f / 17.f);
}

// ---------------------------------------------------------------------------
// K3: 3x3 conv (17 -> 1) + sigmoid -> sa.  (unchanged)
// ---------------------------------------------------------------------------
__global__ __launch_bounds__(256) void k_sa(
    const float* __restrict__ h1, const float* __restrict__ saW,
    const float* __restrict__ sab, float* __restrict__ sa)
{
    __shared__ float S[17 * 3 * 256];
    const int tid = threadIdx.x;
    const int b   = blockIdx.x >> 8;
    const int row = blockIdx.x & 255;

    for (int i = tid; i < 3264; i += 256) {
        const int ch  = i / 192;
        const int rem = i - ch * 192;
        const int dr  = rem >> 6;
        const int c4  = rem & 63;
        const int rr  = row + dr - 1;
        float4 v = {0.f, 0.f, 0.f, 0.f};
        if ((unsigned)rr < 256u)
            v = *(const float4*)(h1 + ((size_t)(b * 17 + ch)) * NPIX + rr * 256 + c4 * 4);
        *(float4*)&S[(ch * 3 + dr) * 256 + c4 * 4] = v;
    }
    __syncthreads();

    const int w = tid;
    float acc = sab[0];
    #pragma unroll 1
    for (int ch = 0; ch < 17; ++ch) {
        #pragma unroll
        for (int dr = 0; dr < 3; ++dr) {
            const float* Sp = &S[(ch * 3 + dr) * 256];
            const float m  = Sp[w];
            const float l  = (w > 0)   ? Sp[w - 1] : 0.f;
            const float r_ = (w < 255) ? Sp[w + 1] : 0.f;
            const float* Wp = saW + (ch * 3 + dr) * 3;
            acc += Wp[0] * l + Wp[1] * m + Wp[2] * r_;
        }
    }
    sa[b * NPIX + row * 256 + w] = 1.f / (1.f + __expf(-acc));
}

// ---------------------------------------------------------------------------
// K4: window scoring MLP + stable-argsort partition.  (unchanged)
// ---------------------------------------------------------------------------
__global__ __launch_bounds__(1024) void k_score_select(
    const float* __restrict__ xm,
    const float* __restrict__ m1W, const float* __restrict__ m1b,
    const float* __restrict__ m2W, const float* __restrict__ m2b,
    int* __restrict__ flag, int* __restrict__ kept)
{
    __shared__ float sc[NW];
    const int b = blockIdx.x;
    const int t = threadIdx.x;
    const int i = t >> 5;
    const int j = t & 31;

    float z[8];
    #pragma unroll
    for (int jj = 0; jj < 8; ++jj) z[jj] = m1b[jj];

    for (int a = 0; a < 8; ++a) {
        #pragma unroll
        for (int cc = 0; cc < 8; ++cc) {
            const float xv = xm[b * NPIX + (i * 8 + a) * 256 + (j * 8 + cc)];
            const int tt = a * 8 + cc;
            #pragma unroll
            for (int jj = 0; jj < 8; ++jj)
                z[jj] += m1W[jj * 64 + tt] * xv;
        }
    }
    #pragma unroll
    for (int jj = 0; jj < 8; ++jj) z[jj] = (z[jj] >= 0.f) ? z[jj] : 0.1f * z[jj];

    float l0 = m2b[0], l1 = m2b[1];
    #pragma unroll
    for (int jj = 0; jj < 8; ++jj) { l0 += m2W[jj] * z[jj]; l1 += m2W[8 + jj] * z[jj]; }
    const float mx = fmaxf(l0, l1);
    const float e0 = expf(l0 - mx), e1 = expf(l1 - mx);
    sc[t] = e0 / (e0 + e1);
    __syncthreads();

    const float s = sc[t];
    int cnt = 0;
    for (int jq = 0; jq < NW; ++jq) {
        const float sj = sc[jq];
        cnt += (sj > s) || (sj == s && jq < t);
    }
    flag[b * NW + t] = (cnt < KEEP) ? 1 : 0;
    if (cnt < KEEP) kept[b * KEEP + cnt] = t;
}

// ---------------------------------------------------------------------------
// K5: windowed attention, LDS-BROADCAST core.
// The readlane design (rounds 0-2) forced a ~90-float live set -> pressure
// spill at the allocator's 64-VGPR target -> scratch-reload serialization
// (VALUBusy 4.4%).  Replacement: all 64 lanes of a wave need the SAME
// K[kl][d] -> a uniform-address ds_read is a hardware broadcast (free).
// K/V rows are contiguous in LDS -> 4x ds_read_b128 each, float4 temps
// consumed immediately (SSA, never addressable -> no scratch).  Live set
// ~62 floats (q16+cw12+vo16+sum+srow+K-temps) fits 64 VGPRs.
// FP order per key is instruction-identical to round 0: kl ascending,
// s = chh+cw then ascending-d dot, sum += e, ascending-d PV.
// rl loop is rolled (srow recomputed inline, same instruction sequence);
// col loop fully unrolled so cw[col]/q[d]/vo[d] stay compile-time-indexed.
// ---------------------------------------------------------------------------
__global__ __launch_bounds__(256) void k_attn(
    const float* __restrict__ qs, const float* __restrict__ ks,
    const float* __restrict__ vs, const int* __restrict__ kept,
    const float* __restrict__ relh, const float* __restrict__ relw,
    float* __restrict__ amix)
{
    __shared__ float SK[72 * PITCH];   // 19584 B
    __shared__ float SV[72 * PITCH];   // 19584 B

    const int b    = blockIdx.y;
    const int win  = kept[b * KEEP + blockIdx.x];
    const int wy = win >> 5, wx = win & 31;
    const int tid  = threadIdx.x;
    const int head = tid >> 6;
    const int lane = tid & 63;
    const int choff = head * 16;
    const size_t bbase = (size_t)b * NPIX;
    const int px0 = (wy * 8) * 256 + wx * 8;      // window origin pixel

    // ---- phase 0: cooperative q stage (64 px x 64 ch = 1024 float4) ----
    #pragma unroll
    for (int it = 0; it < 4; ++it) {
        const int i  = it * 256 + tid;
        const int px = i >> 4;
        const int c4 = i & 15;
        const float4 v = *(const float4*)(
            qs + (bbase + px0 + (px >> 3) * 256 + (px & 7)) * 64 + c4 * 4);
        *(float4*)&SK[px * PITCH + c4 * 4] = v;
    }
    __syncthreads();

    const int qrow = lane >> 3, qcol = lane & 7;
    float q[16];
    #pragma unroll
    for (int j4 = 0; j4 < 4; ++j4) {
        const float4 v = *(const float4*)&SK[(qrow * 8 + qcol) * PITCH + choff + j4 * 4];
        q[j4 * 4 + 0] = v.x * 0.25f; q[j4 * 4 + 1] = v.y * 0.25f;
        q[j4 * 4 + 2] = v.z * 0.25f; q[j4 * 4 + 3] = v.w * 0.25f;
    }

    // ---- column rel-pos coefficients (identical arithmetic to round 0) ----
    float cw[12];
    #pragma unroll
    for (int k = 0; k < 12; ++k) {
        const float* rw = relw + (k - qcol + 11) * 16;
        float sw = 0.f;
        #pragma unroll
        for (int j4 = 0; j4 < 4; ++j4) {
            const float4 w4 = *(const float4*)(rw + j4 * 4);
            sw += q[j4*4+0]*w4.x + q[j4*4+1]*w4.y + q[j4*4+2]*w4.z + q[j4*4+3]*w4.w;
        }
        cw[k] = sw;
    }

    const int wy8 = wy * 8 - 2, wx8 = wx * 8 - 2;

    float sum = 0.f;
    float vo[16];
    #pragma unroll
    for (int d = 0; d < 16; ++d) vo[d] = 0.f;

    #pragma unroll 1
    for (int c = 0; c < 2; ++c) {
        __syncthreads();    // prior LDS reads complete before restaging
        // ---- stage 6 patch rows of K and V (each 72 px x 64 ch) ----
        for (int i = tid; i < 1152; i += 256) {
            const int pxl = i >> 4;             // 0..71
            const int c4  = i & 15;
            const int rl  = pxl / 12;
            const int col = pxl - rl * 12;
            const int ry  = wy8 + 6 * c + rl;
            const int cx  = wx8 + col;
            float4 kv = {0.f,0.f,0.f,0.f}, vv = {0.f,0.f,0.f,0.f};
            if ((unsigned)ry < 256u && (unsigned)cx < 256u) {
                const size_t g = (bbase + ry * 256 + cx) * 64 + c4 * 4;
                kv = *(const float4*)(ks + g);
                vv = *(const float4*)(vs + g);
            }
            *(float4*)&SK[pxl * PITCH + c4 * 4] = kv;
            *(float4*)&SV[pxl * PITCH + c4 * 4] = vv;
        }
        __syncthreads();

        // ---- QK + exp + PV over 72 keys (rows 6c..6c+5) ----
        #pragma unroll 1
        for (int rl = 0; rl < 6; ++rl) {
            // row rel-pos coefficient (same instruction sequence as round 0)
            const float* rh = relh + (c * 6 + rl - qrow + 11) * 16;
            float srow = 0.f;
            #pragma unroll
            for (int j4 = 0; j4 < 4; ++j4) {
                const float4 h4 = *(const float4*)(rh + j4 * 4);
                srow += q[j4*4+0]*h4.x + q[j4*4+1]*h4.y + q[j4*4+2]*h4.z + q[j4*4+3]*h4.w;
            }

            const float* kbase = &SK[(rl * 12) * PITCH + choff];
            const float* vbase = &SV[(rl * 12) * PITCH + choff];
            #pragma unroll
            for (int col = 0; col < 12; ++col) {
                const float* kb = kbase + col * PITCH;   // uniform addr -> broadcast
                const float4 k0 = *(const float4*)(kb + 0);
                const float4 k1 = *(const float4*)(kb + 4);
                const float4 k2 = *(const float4*)(kb + 8);
                const float4 k3 = *(const float4*)(kb + 12);
                float s = srow + cw[col];
                s += k0.x*q[0];  s += k0.y*q[1];  s += k0.z*q[2];  s += k0.w*q[3];
                s += k1.x*q[4];  s += k1.y*q[5];  s += k1.z*q[6];  s += k1.w*q[7];
                s += k2.x*q[8];  s += k2.y*q[9];  s += k2.z*q[10]; s += k2.w*q[11];
                s += k3.x*q[12]; s += k3.y*q[13]; s += k3.z*q[14]; s += k3.w*q[15];
                const float e = __expf(s);
                sum += e;
                const float* vb = vbase + col * PITCH;
                const float4 v0 = *(const float4*)(vb + 0);
                const float4 v1 = *(const float4*)(vb + 4);
                const float4 v2 = *(const float4*)(vb + 8);
                const float4 v3 = *(const float4*)(vb + 12);
                vo[0]  += e*v0.x; vo[1]  += e*v0.y; vo[2]  += e*v0.z; vo[3]  += e*v0.w;
                vo[4]  += e*v1.x; vo[5]  += e*v1.y; vo[6]  += e*v1.z; vo[7]  += e*v1.w;
                vo[8]  += e*v2.x; vo[9]  += e*v2.y; vo[10] += e*v2.z; vo[11] += e*v2.w;
                vo[12] += e*v3.x; vo[13] += e*v3.y; vo[14] += e*v3.z; vo[15] += e*v3.w;
            }
        }
    }

    // ---- epilogue: normalize, transpose via LDS, contiguous stores ----
    const float inv = 1.f / sum;
    __syncthreads();
    #pragma unroll
    for (int j4 = 0; j4 < 4; ++j4) {
        float4 v;
        v.x = vo[j4*4+0] * inv; v.y = vo[j4*4+1] * inv;
        v.z = vo[j4*4+2] * inv; v.w = vo[j4*4+3] * inv;
        *(float4*)&SK[(qrow * 8 + qcol) * PITCH + choff + j4 * 4] = v;
    }
    __syncthreads();
    #pragma unroll
    for (int it = 0; it < 4; ++it) {
        const int i  = it * 256 + tid;
        const int px = i >> 4;
        const int c4 = i & 15;
        const float4 v = *(const float4*)&SK[px * PITCH + c4 * 4];
        *(float4*)(amix + (bbase + px0 + (px >> 3) * 256 + (px & 7)) * 64 + c4 * 4) = v;
    }
}

// ---------------------------------------------------------------------------
// K6: final 1x1 conv (64 -> 64) with fused easy path, og-split like K1.
// xs padded to [64][65] so the NHWC->[ch][px] transpose staging and the
// xs[c][px] reads are both 2-way (free).  Weight offsets scalar via
// readfirstlane(og).  Per-output-element FP order (c ascending, then +bias)
// identical to previous rounds.
// ---------------------------------------------------------------------------
__global__ __launch_bounds__(256) void k_out_f(
    const float* __restrict__ amix, const float* __restrict__ vs,
    const float* __restrict__ sa, const int* __restrict__ flag,
    const float* __restrict__ W, const float* __restrict__ bias,
    float* __restrict__ out)
{
    __shared__ float xs[64][65];                 // 16.6 KB
    __shared__ float smult[64];
    __shared__ int   sflag[64];
    const int tid  = threadIdx.x;
    const int px   = tid & 63;
    const int og   = __builtin_amdgcn_readfirstlane(tid >> 6);
    const int tile = blockIdx.x;
    const int b    = tile >> 10;
    const int p0   = (tile & 1023) << 6;
    const int p    = p0 + px;
    const int gp   = (b << 16) + p;

    // per-pixel flag/mult (4 redundant writers per slot, same value - benign)
    {
        const int h   = p >> 8, w = p & 255;
        const int win = (h >> 3) * 32 + (w >> 3);
        const int fl  = flag[b * NW + win];
        sflag[px] = fl;
        smult[px] = fl ? 1.f : sa[gp];
    }
    __syncthreads();

    // stage 64 px x 64 ch with mult applied; NHWC float4 reads (coalesced
    // 256 B per 16 threads), transposed scalar LDS writes (2-way w/ pad 65)
    #pragma unroll
    for (int it = 0; it < 4; ++it) {
        const int i   = it * 256 + tid;
        const int pxl = i >> 4;
        const int c4  = i & 15;
        const int gpl = (b << 16) + p0 + pxl;
        const float* src = (sflag[pxl] ? amix : vs) + (size_t)gpl * 64;
        const float m = smult[pxl];
        const float4 v = *(const float4*)(src + c4 * 4);
        xs[c4 * 4 + 0][pxl] = v.x * m;
        xs[c4 * 4 + 1][pxl] = v.y * m;
        xs[c4 * 4 + 2][pxl] = v.z * m;
        xs[c4 * 4 + 3][pxl] = v.w * m;
    }
    __syncthreads();

    float acc[16];
    #pragma unroll
    for (int j = 0; j < 16; ++j) acc[j] = 0.f;
    #pragma unroll 2
    for (int c = 0; c < 64; ++c) {
        const float xv = xs[c][px];
        #pragma unroll
        for (int j = 0; j < 16; ++j)
            acc[j] += W[(og * 16 + j) * 64 + c] * xv;
    }

    const int base = (b << 6) * NPIX + p;
    #pragma unroll
    for (int j = 0; j < 16; ++j)
        out[base + (og * 16 + j) * NPIX] = acc[j] + bias[og * 16 + j];
}

// ---------------------------------------------------------------------------
extern "C" void kernel_launch(void* const* d_in, const int* in_sizes, int n_in,
                              void* d_out, int out_size, void* d_ws, size_t ws_size,
                              hipStream_t stream)
{
    const float* x    = (const float*)d_in[0];
    const float* cg   = (const float*)d_in[1];
    const float* Wq   = (const float*)d_in[2];
    const float* bq   = (const float*)d_in[3];
    const float* Wk   = (const float*)d_in[4];
    const float* bk   = (const float*)d_in[5];
    const float* Wv   = (const float*)d_in[6];
    const float* bv   = (const float*)d_in[7];
    const float* Wout = (const float*)d_in[8];
    const float* bout = (const float*)d_in[9];
    const float* relh = (const float*)d_in[10];
    const float* relw = (const float*)d_in[11];
    const float* pinW = (const float*)d_in[12];
    const float* pinb = (const float*)d_in[13];
    const float* lnw  = (const float*)d_in[14];
    const float* lnb  = (const float*)d_in[15];
    const float* saW  = (const float*)d_in[16];
    const float* sab  = (const float*)d_in[17];
    const float* m1W  = (const float*)d_in[18];
    const float* m1b  = (const float*)d_in[19];
    const float* m2W  = (const float*)d_in[20];
    const float* m2b  = (const float*)d_in[21];
    float* out = (float*)d_out;

    // workspace layout (floats); qs doubles as the assembled "amix" tensor
    float* ws    = (float*)d_ws;
    float* qs    = ws;                       // 64*NPIXT (NHWC, aliased amix)
    float* ks    = qs + 8388608;             // NHWC
    float* vs    = ks + 8388608;             // NHWC
    float* h1    = vs + 8388608;             // 17 * NPIXT (NCHW)
    float* xm    = h1 + 17 * NPIXT;          // NPIXT
    float* sa    = xm + NPIXT;               // NPIXT
    int*   flag  = (int*)(sa + NPIXT);       // 2048
    int*   kept  = flag + 2048;              // 1024

    k_qkv         <<<2048, 256, 0, stream>>>(x, Wq, bq, Wk, bk, Wv, bv, qs, ks, vs);
    k_cond        <<<NPIXT / 256, 256, 0, stream>>>(vs, cg, pinW, pinb, lnw, lnb, h1, xm);
    k_sa          <<<512, 256, 0, stream>>>(h1, saW, sab, sa);
    k_score_select<<<2, 1024, 0, stream>>>(xm, m1W, m1b, m2W, m2b, flag, kept);
    k_attn        <<<dim3(KEEP, 2), 256, 0, stream>>>(qs, ks, vs, kept, relh, relw, qs);
    k_out_f       <<<2048, 256, 0, stream>>>(qs, vs, sa, flag, Wout, bout, out);
}

// Round 4
// 366.372 us; speedup vs baseline: 1.8699x; 1.0300x over previous
//
#include <hip/hip_runtime.h>
#include <math.h>

// Problem constants (B=2, H=W=256, DIM=INNER=64, WS=8, OWS=12, HEADS=4, DH=16)
#define NPIX   65536      // 256*256
#define NPIXT  131072     // B * NPIX
#define NW     1024       // 32*32 windows per batch
#define KEEP   512
#define PITCH  68         // LDS row pitch (floats): mult of 4 for float4 ops

// Layouts: x, condition_global, h1, sa, out = NCHW (as given / required).
// qs, ks, vs, amix = NHWC: t[(b*NPIX + p)*64 + c]  (64 contiguous ch/pixel).

// ---------------------------------------------------------------------------
// K1: fused q/k/v 1x1 convs, og-split, NO-SMEM inner loop.
// Round-3 evidence: VALUBusy 24.7% at 50% occupancy with VALU floor ~20us ->
// stall-bound.  Cause: s_load (weights) + ds_read (x) both count in lgkmcnt
// and SMEM returns out-of-order -> compiler must emit lgkmcnt(0) before each
// x-consume, draining all weight prefetches (full SMEM latency per 2-c
// chunk); plus 4 og-waves/CU thrash the 16KB scalar cache (4x12KB).
// Fix: weights live in LDS transposed (Wt[c][o], staged once per m-pass),
// read as uniform ds_read_b128 broadcasts (pure-LDS lgkmcnt, finely
// counted); x read directly from global (coalesced dwords, vmcnt-counted,
// 16KB tile L1-resident across og-waves and m-passes).  Per (m,og,j) the
// c-accumulation is still ascending 0..63 -> bit-identical outputs.
// ---------------------------------------------------------------------------
__global__ __launch_bounds__(256) void k_qkv(
    const float* __restrict__ x,
    const float* __restrict__ Wq, const float* __restrict__ bq,
    const float* __restrict__ Wk, const float* __restrict__ bk,
    const float* __restrict__ Wv, const float* __restrict__ bv,
    float* __restrict__ qs, float* __restrict__ ks, float* __restrict__ vs)
{
    __shared__ float Wt[64][68];                 // 17408 B, transposed weights
    const int tid  = threadIdx.x;
    const int px   = tid & 63;                   // pixel within tile
    const int og   = __builtin_amdgcn_readfirstlane(tid >> 6);  // wave-uniform
    const int tile = blockIdx.x;                 // 0..2047
    const int b    = tile >> 10;
    const int p0   = (tile & 1023) << 6;         // tile's first pixel
    const int gp   = (b << 16) + p0 + px;        // global pixel

    const float* Ws[3]   = {Wq, Wk, Wv};
    const float* bias[3] = {bq, bk, bv};
    float* outs[3] = {qs + (size_t)gp * 64, ks + (size_t)gp * 64, vs + (size_t)gp * 64};
    const float* xg = x + ((size_t)b * 64) * NPIX + p0 + px;
    const int wo = og * 16;

    #pragma unroll
    for (int m = 0; m < 3; ++m) {
        // ---- stage W[m] transposed into LDS (one-time per m-pass) ----
        __syncthreads();   // prior Wt reads complete (no-op for m=0)
        const float* Wm = Ws[m];
        #pragma unroll
        for (int it = 0; it < 4; ++it) {
            const int i  = it * 256 + tid;       // 0..1023
            const int o  = i >> 4;
            const int c4 = i & 15;
            const float4 w = *(const float4*)(Wm + o * 64 + c4 * 4);
            Wt[c4 * 4 + 0][o] = w.x;
            Wt[c4 * 4 + 1][o] = w.y;
            Wt[c4 * 4 + 2][o] = w.z;
            Wt[c4 * 4 + 3][o] = w.w;
        }
        __syncthreads();

        float acc[16];
        #pragma unroll
        for (int j = 0; j < 16; ++j) acc[j] = 0.f;

        // x double-buffered in registers, 8 channels per chunk
        float xr[8];
        #pragma unroll
        for (int k = 0; k < 8; ++k) xr[k] = xg[(size_t)k * NPIX];

        #pragma unroll 2
        for (int cb = 0; cb < 64; cb += 8) {
            float xn[8];
            if (cb + 8 < 64) {
                #pragma unroll
                for (int k = 0; k < 8; ++k) xn[k] = xg[(size_t)(cb + 8 + k) * NPIX];
            }
            #pragma unroll
            for (int k = 0; k < 8; ++k) {
                const int c = cb + k;            // ascending 0..63
                const float xv = xr[k];
                const float4 w0 = *(const float4*)&Wt[c][wo + 0];
                const float4 w1 = *(const float4*)&Wt[c][wo + 4];
                const float4 w2 = *(const float4*)&Wt[c][wo + 8];
                const float4 w3 = *(const float4*)&Wt[c][wo + 12];
                acc[0]  += w0.x * xv; acc[1]  += w0.y * xv;
                acc[2]  += w0.z * xv; acc[3]  += w0.w * xv;
                acc[4]  += w1.x * xv; acc[5]  += w1.y * xv;
                acc[6]  += w1.z * xv; acc[7]  += w1.w * xv;
                acc[8]  += w2.x * xv; acc[9]  += w2.y * xv;
                acc[10] += w2.z * xv; acc[11] += w2.w * xv;
                acc[12] += w3.x * xv; acc[13] += w3.y * xv;
                acc[14] += w3.z * xv; acc[15] += w3.w * xv;
            }
            #pragma unroll
            for (int k = 0; k < 8; ++k) xr[k] = xn[k];
        }

        const float* bb = bias[m];
        #pragma unroll
        for (int j4 = 0; j4 < 4; ++j4) {
            float4 v;
            v.x = acc[j4 * 4 + 0] + bb[wo + j4 * 4 + 0];
            v.y = acc[j4 * 4 + 1] + bb[wo + j4 * 4 + 1];
            v.z = acc[j4 * 4 + 2] + bb[wo + j4 * 4 + 2];
            v.w = acc[j4 * 4 + 3] + bb[wo + j4 * 4 + 3];
            *(float4*)(outs[m] + wo + j4 * 4) = v;
        }
    }
}

// ---------------------------------------------------------------------------
// K2: conditioning conv (68 -> 17) + channel LayerNorm + lrelu; emits xm.
// (arithmetic unchanged; load unroll widened for ILP)
// ---------------------------------------------------------------------------
__global__ __launch_bounds__(256) void k_cond(
    const float* __restrict__ vs, const float* __restrict__ cg,
    const float* __restrict__ pinW, const float* __restrict__ pinb,
    const float* __restrict__ lnw, const float* __restrict__ lnb,
    float* __restrict__ h1, float* __restrict__ xm)
{
    const int gp = blockIdx.x * 256 + threadIdx.x;
    const int b  = gp >> 16;
    const int p  = gp & 65535;
    const int h  = p >> 8;
    const int w  = p & 255;

    float acc[17];
    #pragma unroll
    for (int oc = 0; oc < 17; ++oc) acc[oc] = pinb[oc];

    const float* vp = vs + (size_t)gp * 64;
    #pragma unroll 8
    for (int c4 = 0; c4 < 16; ++c4) {
        const float4 v4 = *(const float4*)(vp + c4 * 4);
        const float vv[4] = {v4.x, v4.y, v4.z, v4.w};
        #pragma unroll
        for (int k = 0; k < 4; ++k) {
            const int c = c4 * 4 + k;
            #pragma unroll
            for (int oc = 0; oc < 17; ++oc)
                acc[oc] += pinW[oc * 68 + c] * vv[k];
        }
    }
    const float c64 = cg[(b * 2 + 0) * NPIX + p];
    const float c65 = cg[(b * 2 + 1) * NPIX + p];
    const float c66 = -1.f + 2.f * (float)(h & 7) / 7.f;
    const float c67 = -1.f + 2.f * (float)(w & 7) / 7.f;
    #pragma unroll
    for (int oc = 0; oc < 17; ++oc)
        acc[oc] += pinW[oc * 68 + 64] * c64 + pinW[oc * 68 + 65] * c65 +
                   pinW[oc * 68 + 66] * c66 + pinW[oc * 68 + 67] * c67;

    float u = 0.f;
    #pragma unroll
    for (int oc = 0; oc < 17; ++oc) u += acc[oc];
    u *= (1.f / 17.f);
    float s = 0.f;
    #pragma unroll
    for (int oc = 0; oc < 17; ++oc) { const float d = acc[oc] - u; s += d * d; }
    s *= (1.f / 17.f);
    const float rstd = rsqrtf(s + 1e-6f);

    float xsum = 0.f;
    #pragma unroll
    for (int oc = 0; oc < 17; ++oc) {
        float hv = lnw[oc] * (acc[oc] - u) * rstd + lnb[oc];
        hv = (hv >= 0.f) ? hv : 0.1f * hv;
        h1[(b * 17 + oc) * NPIX + p] = hv;
        xsum += hv;
    }
    xm[gp] = xsum * (1.f / 17.f);
}

// ---------------------------------------------------------------------------
// K3: 3x3 conv (17 -> 1) + sigmoid -> sa.  (unchanged)
// ---------------------------------------------------------------------------
__global__ __launch_bounds__(256) void k_sa(
    const float* __restrict__ h1, const float* __restrict__ saW,
    const float* __restrict__ sab, float* __restrict__ sa)
{
    __shared__ float S[17 * 3 * 256];
    const int tid = threadIdx.x;
    const int b   = blockIdx.x >> 8;
    const int row = blockIdx.x & 255;

    for (int i = tid; i < 3264; i += 256) {
        const int ch  = i / 192;
        const int rem = i - ch * 192;
        const int dr  = rem >> 6;
        const int c4  = rem & 63;
        const int rr  = row + dr - 1;
        float4 v = {0.f, 0.f, 0.f, 0.f};
        if ((unsigned)rr < 256u)
            v = *(const float4*)(h1 + ((size_t)(b * 17 + ch)) * NPIX + rr * 256 + c4 * 4);
        *(float4*)&S[(ch * 3 + dr) * 256 + c4 * 4] = v;
    }
    __syncthreads();

    const int w = tid;
    float acc = sab[0];
    #pragma unroll 1
    for (int ch = 0; ch < 17; ++ch) {
        #pragma unroll
        for (int dr = 0; dr < 3; ++dr) {
            const float* Sp = &S[(ch * 3 + dr) * 256];
            const float m  = Sp[w];
            const float l  = (w > 0)   ? Sp[w - 1] : 0.f;
            const float r_ = (w < 255) ? Sp[w + 1] : 0.f;
            const float* Wp = saW + (ch * 3 + dr) * 3;
            acc += Wp[0] * l + Wp[1] * m + Wp[2] * r_;
        }
    }
    sa[b * NPIX + row * 256 + w] = 1.f / (1.f + __expf(-acc));
}

// ---------------------------------------------------------------------------
// K4: window scoring MLP + stable-argsort partition.  Scoring arithmetic
// unchanged (bit-identical scores -> identical partition).  The rank loop
// now reads sc[] via float4 (4x fewer LDS ops); comparison results
// identical.
// ---------------------------------------------------------------------------
__global__ __launch_bounds__(1024) void k_score_select(
    const float* __restrict__ xm,
    const float* __restrict__ m1W, const float* __restrict__ m1b,
    const float* __restrict__ m2W, const float* __restrict__ m2b,
    int* __restrict__ flag, int* __restrict__ kept)
{
    __shared__ float sc[NW];
    const int b = blockIdx.x;
    const int t = threadIdx.x;
    const int i = t >> 5;
    const int j = t & 31;

    float z[8];
    #pragma unroll
    for (int jj = 0; jj < 8; ++jj) z[jj] = m1b[jj];

    for (int a = 0; a < 8; ++a) {
        #pragma unroll
        for (int cc = 0; cc < 8; ++cc) {
            const float xv = xm[b * NPIX + (i * 8 + a) * 256 + (j * 8 + cc)];
            const int tt = a * 8 + cc;
            #pragma unroll
            for (int jj = 0; jj < 8; ++jj)
                z[jj] += m1W[jj * 64 + tt] * xv;
        }
    }
    #pragma unroll
    for (int jj = 0; jj < 8; ++jj) z[jj] = (z[jj] >= 0.f) ? z[jj] : 0.1f * z[jj];

    float l0 = m2b[0], l1 = m2b[1];
    #pragma unroll
    for (int jj = 0; jj < 8; ++jj) { l0 += m2W[jj] * z[jj]; l1 += m2W[8 + jj] * z[jj]; }
    const float mx = fmaxf(l0, l1);
    const float e0 = expf(l0 - mx), e1 = expf(l1 - mx);
    sc[t] = e0 / (e0 + e1);
    __syncthreads();

    const float s = sc[t];
    int cnt = 0;
    for (int jq = 0; jq < NW; jq += 4) {
        const float4 s4 = *(const float4*)&sc[jq];
        cnt += (s4.x > s) || (s4.x == s && (jq + 0) < t);
        cnt += (s4.y > s) || (s4.y == s && (jq + 1) < t);
        cnt += (s4.z > s) || (s4.z == s && (jq + 2) < t);
        cnt += (s4.w > s) || (s4.w == s && (jq + 3) < t);
    }
    flag[b * NW + t] = (cnt < KEEP) ? 1 : 0;
    if (cnt < KEEP) kept[b * KEEP + cnt] = t;
}

// ---------------------------------------------------------------------------
// K5: windowed attention, LDS-broadcast core (round-3 structure) with:
//   (1) chunk halved to 3 patch rows (36 px) -> LDS 39.4KB -> 19.6KB,
//       blocks/CU 4 -> 7-8 (occupancy 24% -> ~50%, the grid is 1024);
//   (2) q loaded directly from global (no LDS stage, one less barrier).
// Key order preserved: 4 chunks x rl 0..2 x col 0..11 = same ascending
// kl 0..143; per-key arithmetic instruction-identical -> bit-identical.
// Epilogue transpose uses the flat 4896-float S buffer (needs 4352).
// ---------------------------------------------------------------------------
__global__ __launch_bounds__(256) void k_attn(
    const float* __restrict__ qs, const float* __restrict__ ks,
    const float* __restrict__ vs, const int* __restrict__ kept,
    const float* __restrict__ relh, const float* __restrict__ relw,
    float* __restrict__ amix)
{
    __shared__ float S[2 * 36 * PITCH];   // 19584 B total (SK | SV)
    float* SK = S;
    float* SV = S + 36 * PITCH;

    const int b    = blockIdx.y;
    const int win  = kept[b * KEEP + blockIdx.x];
    const int wy = win >> 5, wx = win & 31;
    const int tid  = threadIdx.x;
    const int head = tid >> 6;
    const int lane = tid & 63;
    const int choff = head * 16;
    const size_t bbase = (size_t)b * NPIX;
    const int px0 = (wy * 8) * 256 + wx * 8;      // window origin pixel
    const int qrow = lane >> 3, qcol = lane & 7;

    // ---- q direct from global (identical values: same source, x0.25) ----
    float q[16];
    {
        const float* qp = qs + (bbase + px0 + qrow * 256 + qcol) * 64 + choff;
        #pragma unroll
        for (int j4 = 0; j4 < 4; ++j4) {
            const float4 v = *(const float4*)(qp + j4 * 4);
            q[j4 * 4 + 0] = v.x * 0.25f; q[j4 * 4 + 1] = v.y * 0.25f;
            q[j4 * 4 + 2] = v.z * 0.25f; q[j4 * 4 + 3] = v.w * 0.25f;
        }
    }

    // ---- column rel-pos coefficients (identical arithmetic) ----
    float cw[12];
    #pragma unroll
    for (int k = 0; k < 12; ++k) {
        const float* rw = relw + (k - qcol + 11) * 16;
        float sw = 0.f;
        #pragma unroll
        for (int j4 = 0; j4 < 4; ++j4) {
            const float4 w4 = *(const float4*)(rw + j4 * 4);
            sw += q[j4*4+0]*w4.x + q[j4*4+1]*w4.y + q[j4*4+2]*w4.z + q[j4*4+3]*w4.w;
        }
        cw[k] = sw;
    }

    const int wy8 = wy * 8 - 2, wx8 = wx * 8 - 2;

    float sum = 0.f;
    float vo[16];
    #pragma unroll
    for (int d = 0; d < 16; ++d) vo[d] = 0.f;

    #pragma unroll 1
    for (int cc = 0; cc < 4; ++cc) {
        __syncthreads();    // prior LDS reads complete before restaging
        // ---- stage 3 patch rows of K and V (each 36 px x 64 ch) ----
        for (int i = tid; i < 576; i += 256) {
            const int pxl = i >> 4;             // 0..35
            const int c4  = i & 15;
            const int rl  = pxl / 12;
            const int col = pxl - rl * 12;
            const int ry  = wy8 + 3 * cc + rl;
            const int cx  = wx8 + col;
            float4 kv = {0.f,0.f,0.f,0.f}, vv = {0.f,0.f,0.f,0.f};
            if ((unsigned)ry < 256u && (unsigned)cx < 256u) {
                const size_t g = (bbase + ry * 256 + cx) * 64 + c4 * 4;
                kv = *(const float4*)(ks + g);
                vv = *(const float4*)(vs + g);
            }
            *(float4*)&SK[pxl * PITCH + c4 * 4] = kv;
            *(float4*)&SV[pxl * PITCH + c4 * 4] = vv;
        }
        __syncthreads();

        // ---- QK + exp + PV over 36 keys (patch rows 3cc..3cc+2) ----
        #pragma unroll 1
        for (int rl = 0; rl < 3; ++rl) {
            // row rel-pos coefficient (same instruction sequence)
            const float* rh = relh + (3 * cc + rl - qrow + 11) * 16;
            float srow = 0.f;
            #pragma unroll
            for (int j4 = 0; j4 < 4; ++j4) {
                const float4 h4 = *(const float4*)(rh + j4 * 4);
                srow += q[j4*4+0]*h4.x + q[j4*4+1]*h4.y + q[j4*4+2]*h4.z + q[j4*4+3]*h4.w;
            }

            const float* kbase = &SK[(rl * 12) * PITCH + choff];
            const float* vbase = &SV[(rl * 12) * PITCH + choff];
            #pragma unroll
            for (int col = 0; col < 12; ++col) {
                const float* kb = kbase + col * PITCH;   // uniform addr -> broadcast
                const float4 k0 = *(const float4*)(kb + 0);
                const float4 k1 = *(const float4*)(kb + 4);
                const float4 k2 = *(const float4*)(kb + 8);
                const float4 k3 = *(const float4*)(kb + 12);
                float s = srow + cw[col];
                s += k0.x*q[0];  s += k0.y*q[1];  s += k0.z*q[2];  s += k0.w*q[3];
                s += k1.x*q[4];  s += k1.y*q[5];  s += k1.z*q[6];  s += k1.w*q[7];
                s += k2.x*q[8];  s += k2.y*q[9];  s += k2.z*q[10]; s += k2.w*q[11];
                s += k3.x*q[12]; s += k3.y*q[13]; s += k3.z*q[14]; s += k3.w*q[15];
                const float e = __expf(s);
                sum += e;
                const float* vb = vbase + col * PITCH;
                const float4 v0 = *(const float4*)(vb + 0);
                const float4 v1 = *(const float4*)(vb + 4);
                const float4 v2 = *(const float4*)(vb + 8);
                const float4 v3 = *(const float4*)(vb + 12);
                vo[0]  += e*v0.x; vo[1]  += e*v0.y; vo[2]  += e*v0.z; vo[3]  += e*v0.w;
                vo[4]  += e*v1.x; vo[5]  += e*v1.y; vo[6]  += e*v1.z; vo[7]  += e*v1.w;
                vo[8]  += e*v2.x; vo[9]  += e*v2.y; vo[10] += e*v2.z; vo[11] += e*v2.w;
                vo[12] += e*v3.x; vo[13] += e*v3.y; vo[14] += e*v3.z; vo[15] += e*v3.w;
            }
        }
    }

    // ---- epilogue: normalize, transpose via flat S, contiguous stores ----
    const float inv = 1.f / sum;
    __syncthreads();
    #pragma unroll
    for (int j4 = 0; j4 < 4; ++j4) {
        float4 v;
        v.x = vo[j4*4+0] * inv; v.y = vo[j4*4+1] * inv;
        v.z = vo[j4*4+2] * inv; v.w = vo[j4*4+3] * inv;
        *(float4*)&S[(qrow * 8 + qcol) * PITCH + choff + j4 * 4] = v;
    }
    __syncthreads();
    #pragma unroll
    for (int it = 0; it < 4; ++it) {
        const int i  = it * 256 + tid;
        const int px = i >> 4;
        const int c4 = i & 15;
        const float4 v = *(const float4*)&S[px * PITCH + c4 * 4];
        *(float4*)(amix + (bbase + px0 + (px >> 3) * 256 + (px & 7)) * 64 + c4 * 4) = v;
    }
}

// ---------------------------------------------------------------------------
// K6: final 1x1 conv (64 -> 64) with fused easy path, og-split, NO-SMEM
// inner loop (same lgkmcnt-mixing fix as K1: Wout transposed into LDS once,
// weights read as uniform ds_read_b128 broadcasts).  Per-output FP order
// (c ascending, then +bias) identical to previous rounds.
// ---------------------------------------------------------------------------
__global__ __launch_bounds__(256) void k_out_f(
    const float* __restrict__ amix, const float* __restrict__ vs,
    const float* __restrict__ sa, const int* __restrict__ flag,
    const float* __restrict__ W, const float* __restrict__ bias,
    float* __restrict__ out)
{
    __shared__ float xs[64][65];                 // 16640 B
    __shared__ float Wt[64][68];                 // 17408 B
    __shared__ float smult[64];
    __shared__ int   sflag[64];
    const int tid  = threadIdx.x;
    const int px   = tid & 63;
    const int og   = __builtin_amdgcn_readfirstlane(tid >> 6);
    const int tile = blockIdx.x;
    const int b    = tile >> 10;
    const int p0   = (tile & 1023) << 6;
    const int p    = p0 + px;
    const int gp   = (b << 16) + p;
    const int wo   = og * 16;

    // ---- stage Wout transposed (one-time) ----
    #pragma unroll
    for (int it = 0; it < 4; ++it) {
        const int i  = it * 256 + tid;
        const int o  = i >> 4;
        const int c4 = i & 15;
        const float4 w = *(const float4*)(W + o * 64 + c4 * 4);
        Wt[c4 * 4 + 0][o] = w.x;
        Wt[c4 * 4 + 1][o] = w.y;
        Wt[c4 * 4 + 2][o] = w.z;
        Wt[c4 * 4 + 3][o] = w.w;
    }

    // per-pixel flag/mult (4 redundant writers per slot, same value - benign)
    {
        const int h   = p >> 8, w_ = p & 255;
        const int win = (h >> 3) * 32 + (w_ >> 3);
        const int fl  = flag[b * NW + win];
        sflag[px] = fl;
        smult[px] = fl ? 1.f : sa[gp];
    }
    __syncthreads();

    // stage 64 px x 64 ch with mult applied; NHWC float4 reads (coalesced),
    // transposed scalar LDS writes (2-way w/ pad 65)
    #pragma unroll
    for (int it = 0; it < 4; ++it) {
        const int i   = it * 256 + tid;
        const int pxl = i >> 4;
        const int c4  = i & 15;
        const int gpl = (b << 16) + p0 + pxl;
        const float* src = (sflag[pxl] ? amix : vs) + (size_t)gpl * 64;
        const float m = smult[pxl];
        const float4 v = *(const float4*)(src + c4 * 4);
        xs[c4 * 4 + 0][pxl] = v.x * m;
        xs[c4 * 4 + 1][pxl] = v.y * m;
        xs[c4 * 4 + 2][pxl] = v.z * m;
        xs[c4 * 4 + 3][pxl] = v.w * m;
    }
    __syncthreads();

    float acc[16];
    #pragma unroll
    for (int j = 0; j < 16; ++j) acc[j] = 0.f;
    #pragma unroll 4
    for (int c = 0; c < 64; ++c) {
        const float xv = xs[c][px];
        const float4 w0 = *(const float4*)&Wt[c][wo + 0];
        const float4 w1 = *(const float4*)&Wt[c][wo + 4];
        const float4 w2 = *(const float4*)&Wt[c][wo + 8];
        const float4 w3 = *(const float4*)&Wt[c][wo + 12];
        acc[0]  += w0.x * xv; acc[1]  += w0.y * xv;
        acc[2]  += w0.z * xv; acc[3]  += w0.w * xv;
        acc[4]  += w1.x * xv; acc[5]  += w1.y * xv;
        acc[6]  += w1.z * xv; acc[7]  += w1.w * xv;
        acc[8]  += w2.x * xv; acc[9]  += w2.y * xv;
        acc[10] += w2.z * xv; acc[11] += w2.w * xv;
        acc[12] += w3.x * xv; acc[13] += w3.y * xv;
        acc[14] += w3.z * xv; acc[15] += w3.w * xv;
    }

    const int base = (b << 6) * NPIX + p;
    #pragma unroll
    for (int j = 0; j < 16; ++j)
        out[base + (wo + j) * NPIX] = acc[j] + bias[wo + j];
}

// ---------------------------------------------------------------------------
extern "C" void kernel_launch(void* const* d_in, const int* in_sizes, int n_in,
                              void* d_out, int out_size, void* d_ws, size_t ws_size,
                              hipStream_t stream)
{
    const float* x    = (const float*)d_in[0];
    const float* cg   = (const float*)d_in[1];
    const float* Wq   = (const float*)d_in[2];
    const float* bq   = (const float*)d_in[3];
    const float* Wk   = (const float*)d_in[4];
    const float* bk   = (const float*)d_in[5];
    const float* Wv   = (const float*)d_in[6];
    const float* bv   = (const float*)d_in[7];
    const float* Wout = (const float*)d_in[8];
    const float* bout = (const float*)d_in[9];
    const float* relh = (const float*)d_in[10];
    const float* relw = (const float*)d_in[11];
    const float* pinW = (const float*)d_in[12];
    const float* pinb = (const float*)d_in[13];
    const float* lnw  = (const float*)d_in[14];
    const float* lnb  = (const float*)d_in[15];
    const float* saW  = (const float*)d_in[16];
    const float* sab  = (const float*)d_in[17];
    const float* m1W  = (const float*)d_in[18];
    const float* m1b  = (const float*)d_in[19];
    const float* m2W  = (const float*)d_in[20];
    const float* m2b  = (const float*)d_in[21];
    float* out = (float*)d_out;

    // workspace layout (floats); qs doubles as the assembled "amix" tensor
    float* ws    = (float*)d_ws;
    float* qs    = ws;                       // 64*NPIXT (NHWC, aliased amix)
    float* ks    = qs + 8388608;             // NHWC
    float* vs    = ks + 8388608;             // NHWC
    float* h1    = vs + 8388608;             // 17 * NPIXT (NCHW)
    float* xm    = h1 + 17 * NPIXT;          // NPIXT
    float* sa    = xm + NPIXT;               // NPIXT
    int*   flag  = (int*)(sa + NPIXT);       // 2048
    int*   kept  = flag + 2048;              // 1024

    k_qkv         <<<2048, 256, 0, stream>>>(x, Wq, bq, Wk, bk, Wv, bv, qs, ks, vs);
    k_cond        <<<NPIXT / 256, 256, 0, stream>>>(vs, cg, pinW, pinb, lnw, lnb, h1, xm);
    k_sa          <<<512, 256, 0, stream>>>(h1, saW, sab, sa);
    k_score_select<<<2, 1024, 0, stream>>>(xm, m1W, m1b, m2W, m2b, flag, kept);
    k_attn        <<<dim3(KEEP, 2), 256, 0, stream>>>(qs, ks, vs, kept, relh, relw, qs);
    k_out_f       <<<2048, 256, 0, stream>>>(qs, vs, sa, flag, Wout, bout, out);
}